// Round 1
// baseline (679.852 us; speedup 1.0000x reference)
//
#include <hip/hip_runtime.h>
#include <hip/hip_bf16.h>

#define F_IN 512
#define NC 64      // HID == N_CLS == 64
#define NITER 10

// ---------------------------------------------------------------------------
// Init per-node halting state; also set rowptr[N] = E.
__global__ __launch_bounds__(256) void init_state_kernel(
    float* __restrict__ steps, float* __restrict__ sumh, int* __restrict__ cont,
    int* __restrict__ rowptr, int N, int E) {
  int i = blockIdx.x * blockDim.x + threadIdx.x;
  if (i < N) { steps[i] = 1.0f; sumh[i] = 0.0f; cont[i] = 1; }
  if (i == 0) rowptr[N] = E;
}

// ---------------------------------------------------------------------------
// Fused MLP: prop0[r,:] = relu(x[r,:] @ W1 + b1) @ W2 + b2   (all fp32)
// Thread-per-row. W1/W2/b1/b2 accesses are wave-uniform -> scalar cache.
__global__ __launch_bounds__(256) void mlp_kernel(
    const float* __restrict__ x, const float* __restrict__ W1,
    const float* __restrict__ b1, const float* __restrict__ W2,
    const float* __restrict__ b2, float* __restrict__ out, int N) {
  int r = blockIdx.x * blockDim.x + threadIdx.x;
  if (r >= N) return;
  const float* xr = x + (size_t)r * F_IN;
  float h[NC];
#pragma unroll
  for (int j = 0; j < NC; ++j) h[j] = b1[j];
  for (int k0 = 0; k0 < F_IN; k0 += 4) {
    float4 xv = *reinterpret_cast<const float4*>(xr + k0);
    float xs[4] = {xv.x, xv.y, xv.z, xv.w};
#pragma unroll
    for (int kk = 0; kk < 4; ++kk) {
      const float* w1row = W1 + (size_t)(k0 + kk) * NC;
      float xk = xs[kk];
#pragma unroll
      for (int j = 0; j < NC; ++j) h[j] = fmaf(xk, w1row[j], h[j]);
    }
  }
#pragma unroll
  for (int j = 0; j < NC; ++j) h[j] = fmaxf(h[j], 0.0f);
  float* orow = out + (size_t)r * NC;
#pragma unroll
  for (int jc = 0; jc < NC; jc += 16) {
    float o[16];
#pragma unroll
    for (int jj = 0; jj < 16; ++jj) o[jj] = b2[jc + jj];
    for (int m = 0; m < NC; ++m) {
      float hm = h[m];
      const float* w2row = W2 + (size_t)m * NC + jc;
#pragma unroll
      for (int jj = 0; jj < 16; ++jj) o[jj] = fmaf(hm, w2row[jj], o[jj]);
    }
#pragma unroll
    for (int jj = 0; jj < 16; ++jj) orow[jc + jj] = o[jj];
  }
}

// ---------------------------------------------------------------------------
// Degree histograms: deg_i counts sources (for GCN norm), indeg counts
// destinations (for the pull-CSR). Int atomics -> deterministic.
__global__ __launch_bounds__(256) void hist_kernel(
    const int* __restrict__ ei, int* __restrict__ deg_i,
    int* __restrict__ indeg, int E) {
  int e = blockIdx.x * blockDim.x + threadIdx.x;
  if (e < E) {
    atomicAdd(&deg_i[ei[e]], 1);       // row = edge_index[0]
    atomicAdd(&indeg[ei[E + e]], 1);   // col = edge_index[1]
  }
}

// dis[i] = 1/sqrt(deg_i[i] + 1)   (+1 = self loop; deg always >= 1)
__global__ __launch_bounds__(256) void dis_kernel(
    const int* __restrict__ deg_i, float* __restrict__ dis, int N) {
  int i = blockIdx.x * blockDim.x + threadIdx.x;
  if (i < N) dis[i] = 1.0f / sqrtf((float)(deg_i[i] + 1));
}

// ---------------------------------------------------------------------------
// 3-kernel exclusive scan of indeg -> rowptr  (N = 50000, 196 blocks of 256)
__global__ __launch_bounds__(256) void scan_sum_kernel(
    const int* __restrict__ indeg, int* __restrict__ bsum, int N) {
  __shared__ int sm[256];
  int tid = threadIdx.x;
  int i = blockIdx.x * 256 + tid;
  sm[tid] = (i < N) ? indeg[i] : 0;
  __syncthreads();
  for (int s = 128; s > 0; s >>= 1) {
    if (tid < s) sm[tid] += sm[tid + s];
    __syncthreads();
  }
  if (tid == 0) bsum[blockIdx.x] = sm[0];
}

__global__ __launch_bounds__(256) void scan_bsum_kernel(int* __restrict__ bsum, int nb) {
  __shared__ int sm[256];
  int tid = threadIdx.x;
  int v = (tid < nb) ? bsum[tid] : 0;
  sm[tid] = v;
  __syncthreads();
  for (int s = 1; s < 256; s <<= 1) {
    int t = (tid >= s) ? sm[tid - s] : 0;
    __syncthreads();
    sm[tid] += t;
    __syncthreads();
  }
  if (tid < nb) bsum[tid] = sm[tid] - v;  // exclusive
}

__global__ __launch_bounds__(256) void scan_final_kernel(
    const int* __restrict__ indeg, const int* __restrict__ bsum,
    int* __restrict__ rowptr, int N) {
  __shared__ int sm[256];
  int tid = threadIdx.x;
  int i = blockIdx.x * 256 + tid;
  int v = (i < N) ? indeg[i] : 0;
  sm[tid] = v;
  __syncthreads();
  for (int s = 1; s < 256; s <<= 1) {
    int t = (tid >= s) ? sm[tid - s] : 0;
    __syncthreads();
    sm[tid] += t;
    __syncthreads();
  }
  if (i < N) rowptr[i] = bsum[blockIdx.x] + sm[tid] - v;
}

// ---------------------------------------------------------------------------
// Build destination-CSR entries: csr[pos] = {src, norm} packed as int2.
__global__ __launch_bounds__(256) void scatter_kernel(
    const int* __restrict__ ei, const int* __restrict__ rowptr,
    int* __restrict__ cursor, const float* __restrict__ dis,
    int2* __restrict__ csr, int E) {
  int e = blockIdx.x * blockDim.x + threadIdx.x;
  if (e < E) {
    int s = ei[e];
    int c = ei[E + e];
    int pos = rowptr[c] + atomicAdd(&cursor[c], 1);
    csr[pos] = make_int2(s, __float_as_int(dis[s] * dis[c]));
  }
}

// ---------------------------------------------------------------------------
// One adaptive-propagation step, fully fused. One 64-lane wave per node,
// lane = feature. Pull-based gather over incoming edges, no atomics.
__global__ __launch_bounds__(256) void prop_step_kernel(
    const float* __restrict__ prop, float* __restrict__ prop_new,
    const int2* __restrict__ csr, const int* __restrict__ rowptr,
    const float* __restrict__ dis, const float* __restrict__ hw,
    const float* __restrict__ hb, float* __restrict__ steps,
    float* __restrict__ sumh, int* __restrict__ cont,
    float* __restrict__ xacc, int N) {
  int wid = (int)((blockIdx.x * blockDim.x + threadIdx.x) >> 6);
  if (wid >= N) return;
  int lane = threadIdx.x & 63;
  size_t rowoff = (size_t)wid * NC + lane;

  float oldv = prop[rowoff];
  float dc = dis[wid];
  int beg = __builtin_amdgcn_readfirstlane(rowptr[wid]);
  int end = __builtin_amdgcn_readfirstlane(rowptr[wid + 1]);

  // self-loop: norm = dis[c]^2
  float a0 = dc * dc * oldv, a1 = 0.f, a2 = 0.f, a3 = 0.f;
  int i = beg;
  for (; i + 4 <= end; i += 4) {   // 4-way unroll: 4 outstanding gathers
    int2 e0 = csr[i], e1 = csr[i + 1], e2 = csr[i + 2], e3 = csr[i + 3];
    a0 = fmaf(__int_as_float(e0.y), prop[(size_t)e0.x * NC + lane], a0);
    a1 = fmaf(__int_as_float(e1.y), prop[(size_t)e1.x * NC + lane], a1);
    a2 = fmaf(__int_as_float(e2.y), prop[(size_t)e2.x * NC + lane], a2);
    a3 = fmaf(__int_as_float(e3.y), prop[(size_t)e3.x * NC + lane], a3);
  }
  for (; i < end; ++i) {
    int2 e0 = csr[i];
    a0 = fmaf(__int_as_float(e0.y), prop[(size_t)e0.x * NC + lane], a0);
  }
  float acc = (a0 + a1) + (a2 + a3);
  prop_new[rowoff] = acc;

  // hh = sigmoid(prop_new[c,:] . halt_w + halt_b)
  float z = acc * hw[lane];
#pragma unroll
  for (int off = 32; off > 0; off >>= 1) z += __shfl_xor(z, off);
  z += hb[0];
  float hh = 1.0f / (1.0f + expf(-z));

  float st = steps[wid], sh = sumh[wid];
  int ct = cont[wid];
  bool prob = ((sh + hh) < 0.99f) && (ct != 0);
  float pf = prob ? 1.0f : 0.0f;
  st += pf;
  sh += pf * hh;
  bool cond = prob && (st < (float)NITER);
  float pp = cond ? sh : (1.0f - sh);
  float ctf = ct ? 1.0f : 0.0f;
  xacc[rowoff] += (acc * pp + oldv * (1.0f - pp)) * ctf;
  if (lane == 0) { steps[wid] = st; sumh[wid] = sh; cont[wid] = prob ? 1 : 0; }
}

// ---------------------------------------------------------------------------
// out0 = log_softmax(xacc/steps), out1 = steps, out2 = 1 - sum_h
__global__ __launch_bounds__(256) void final_kernel(
    const float* __restrict__ xacc, const float* __restrict__ steps,
    const float* __restrict__ sumh, float* __restrict__ out0,
    float* __restrict__ out1, float* __restrict__ out2, int N) {
  int wid = (int)((blockIdx.x * blockDim.x + threadIdx.x) >> 6);
  if (wid >= N) return;
  int lane = threadIdx.x & 63;
  float st = steps[wid];
  float v = xacc[(size_t)wid * NC + lane] / st;
  float m = v;
#pragma unroll
  for (int off = 32; off > 0; off >>= 1) m = fmaxf(m, __shfl_xor(m, off));
  float e = expf(v - m);
  float s = e;
#pragma unroll
  for (int off = 32; off > 0; off >>= 1) s += __shfl_xor(s, off);
  out0[(size_t)wid * NC + lane] = v - m - logf(s);
  if (lane == 0) { out1[wid] = st; out2[wid] = 1.0f - sumh[wid]; }
}

// ---------------------------------------------------------------------------
extern "C" void kernel_launch(void* const* d_in, const int* in_sizes, int n_in,
                              void* d_out, int out_size, void* d_ws, size_t ws_size,
                              hipStream_t stream) {
  const float* x      = (const float*)d_in[0];
  const int*   ei     = (const int*)d_in[1];
  const float* W1     = (const float*)d_in[2];
  const float* b1     = (const float*)d_in[3];
  const float* W2     = (const float*)d_in[4];
  const float* b2     = (const float*)d_in[5];
  const float* halt_w = (const float*)d_in[6];
  const float* halt_b = (const float*)d_in[7];

  const int N = in_sizes[0] / F_IN;   // 50000
  const int E = in_sizes[1] / 2;      // 800000

  // workspace carve-up (256B aligned)
  char* p = (char*)d_ws;
  auto alloc = [&](size_t bytes) {
    void* r = (void*)p;
    p += (bytes + 255) & ~(size_t)255;
    return r;
  };
  float* propA  = (float*)alloc((size_t)N * NC * 4);
  float* propB  = (float*)alloc((size_t)N * NC * 4);
  float* xacc   = (float*)alloc((size_t)N * NC * 4);
  int2*  csr    = (int2*)alloc((size_t)E * 8);
  int*   rowptr = (int*)alloc((size_t)(N + 1) * 4);
  int*   deg_i  = (int*)alloc((size_t)N * 4);
  int*   indeg  = (int*)alloc((size_t)N * 4);
  int*   cursor = (int*)alloc((size_t)N * 4);
  float* dis    = (float*)alloc((size_t)N * 4);
  float* steps  = (float*)alloc((size_t)N * 4);
  float* sumh   = (float*)alloc((size_t)N * 4);
  int*   cont   = (int*)alloc((size_t)N * 4);
  int*   bsum   = (int*)alloc(1024);

  hipMemsetAsync(deg_i,  0, (size_t)N * 4, stream);
  hipMemsetAsync(indeg,  0, (size_t)N * 4, stream);
  hipMemsetAsync(cursor, 0, (size_t)N * 4, stream);
  hipMemsetAsync(xacc,   0, (size_t)N * NC * 4, stream);

  const int nbN = (N + 255) / 256;   // 196
  const int nbE = (E + 255) / 256;   // 3125

  init_state_kernel<<<nbN, 256, 0, stream>>>(steps, sumh, cont, rowptr, N, E);
  mlp_kernel<<<nbN, 256, 0, stream>>>(x, W1, b1, W2, b2, propA, N);
  hist_kernel<<<nbE, 256, 0, stream>>>(ei, deg_i, indeg, E);
  dis_kernel<<<nbN, 256, 0, stream>>>(deg_i, dis, N);
  scan_sum_kernel<<<nbN, 256, 0, stream>>>(indeg, bsum, N);
  scan_bsum_kernel<<<1, 256, 0, stream>>>(bsum, nbN);
  scan_final_kernel<<<nbN, 256, 0, stream>>>(indeg, bsum, rowptr, N);
  scatter_kernel<<<nbE, 256, 0, stream>>>(ei, rowptr, cursor, dis, csr, E);

  float* out0 = (float*)d_out;
  float* out1 = out0 + (size_t)N * NC;
  float* out2 = out1 + N;

  const float* cur = propA;
  float* nxt = propB;
  const int nbW = (N + 3) / 4;       // 4 waves (nodes) per 256-thread block
  for (int it = 0; it < NITER; ++it) {
    prop_step_kernel<<<nbW, 256, 0, stream>>>(cur, nxt, csr, rowptr, dis,
                                              halt_w, halt_b, steps, sumh,
                                              cont, xacc, N);
    const float* t = nxt; nxt = (float*)cur; cur = t;
  }
  final_kernel<<<nbW, 256, 0, stream>>>(xacc, steps, sumh, out0, out1, out2, N);
}

// Round 2
// 588.126 us; speedup vs baseline: 1.1560x; 1.1560x over previous
//
#include <hip/hip_runtime.h>
#include <hip/hip_bf16.h>

#define F_IN 512
#define NC 64      // HID == N_CLS == 64
#define NITER 10
#define BM 128     // MLP tile rows
#define BK 64      // MLP K tile
#define XS 132     // LDS transposed-tile stride (132*4B = 33*16B: keeps b128 align)

// ---------------------------------------------------------------------------
// Init per-node halting state; also set rowptr[N] = E.
__global__ __launch_bounds__(256) void init_state_kernel(
    float* __restrict__ steps, float* __restrict__ sumh, int* __restrict__ cont,
    int* __restrict__ rowptr, int N, int E) {
  int i = blockIdx.x * blockDim.x + threadIdx.x;
  if (i < N) { steps[i] = 1.0f; sumh[i] = 0.0f; cont[i] = 1; }
  if (i == 0) rowptr[N] = E;
}

// ---------------------------------------------------------------------------
// Fused tiled MLP: out[r,:] = relu(x[r,:] @ W1 + b1) @ W2 + b2   (all fp32)
// Block: 128 rows x 64 cols, 256 threads, 8x4 outputs per thread.
// x tile staged transposed in LDS (xT[k][row]); W tiles staged row-major.
// GEMM2 fused: h goes through LDS (transposed), W2 reuses the W-tile buffer.
__global__ __launch_bounds__(256) void mlp_kernel(
    const float* __restrict__ x, const float* __restrict__ W1,
    const float* __restrict__ b1, const float* __restrict__ W2,
    const float* __restrict__ b2, float* __restrict__ out, int N) {
  __shared__ float xT[BK * XS];    // [k][row] transposed x tile / later hT[j][row]
  __shared__ float ws[BK * NC];    // W1 k-tile / later W2
  const int tid  = threadIdx.x;
  const int brow = blockIdx.x * BM;
  const int r0 = (tid >> 4) * 8;   // 16 row-groups of 8
  const int c0 = (tid & 15) * 4;   // 16 col-groups of 4

  float acc[8][4];
#pragma unroll
  for (int j = 0; j < 4; ++j) {
    float bv = b1[c0 + j];
#pragma unroll
    for (int i = 0; i < 8; ++i) acc[i][j] = bv;
  }

  for (int kt = 0; kt < F_IN; kt += BK) {
    // stage x tile (128 rows x 64 k), transposed into xT
#pragma unroll
    for (int q = 0; q < 8; ++q) {
      int fidx = q * 256 + tid;          // over 2048 float4s
      int row = fidx >> 4, kq = fidx & 15;
      int gr = brow + row; if (gr >= N) gr = N - 1;
      float4 v = *reinterpret_cast<const float4*>(&x[(size_t)gr * F_IN + kt + kq * 4]);
      xT[(kq * 4 + 0) * XS + row] = v.x;
      xT[(kq * 4 + 1) * XS + row] = v.y;
      xT[(kq * 4 + 2) * XS + row] = v.z;
      xT[(kq * 4 + 3) * XS + row] = v.w;
    }
    // stage W1 k-tile (64 x 64), row-major
#pragma unroll
    for (int q = 0; q < 4; ++q) {
      int fidx = q * 256 + tid;          // over 1024 float4s
      int row = fidx >> 4, kq = fidx & 15;
      *reinterpret_cast<float4*>(&ws[row * NC + kq * 4]) =
          *reinterpret_cast<const float4*>(&W1[(size_t)(kt + row) * NC + kq * 4]);
    }
    __syncthreads();
#pragma unroll 4
    for (int k = 0; k < BK; ++k) {
      float4 xa = *reinterpret_cast<const float4*>(&xT[k * XS + r0]);
      float4 xb = *reinterpret_cast<const float4*>(&xT[k * XS + r0 + 4]);
      float4 wv = *reinterpret_cast<const float4*>(&ws[k * NC + c0]);
      float xr[8] = {xa.x, xa.y, xa.z, xa.w, xb.x, xb.y, xb.z, xb.w};
      float wr[4] = {wv.x, wv.y, wv.z, wv.w};
#pragma unroll
      for (int i = 0; i < 8; ++i)
#pragma unroll
        for (int j = 0; j < 4; ++j) acc[i][j] = fmaf(xr[i], wr[j], acc[i][j]);
    }
    __syncthreads();
  }

  // ReLU; write h transposed into xT space (hT[j][row]); stage W2 into ws
#pragma unroll
  for (int i = 0; i < 8; ++i)
#pragma unroll
    for (int j = 0; j < 4; ++j)
      xT[(c0 + j) * XS + (r0 + i)] = fmaxf(acc[i][j], 0.0f);
#pragma unroll
  for (int q = 0; q < 4; ++q) {
    int fidx = q * 256 + tid;
    int row = fidx >> 4, kq = fidx & 15;
    *reinterpret_cast<float4*>(&ws[row * NC + kq * 4]) =
        *reinterpret_cast<const float4*>(&W2[(size_t)row * NC + kq * 4]);
  }
  float acc2[8][4];
#pragma unroll
  for (int j = 0; j < 4; ++j) {
    float bv = b2[c0 + j];
#pragma unroll
    for (int i = 0; i < 8; ++i) acc2[i][j] = bv;
  }
  __syncthreads();
#pragma unroll 4
  for (int k = 0; k < NC; ++k) {
    float4 xa = *reinterpret_cast<const float4*>(&xT[k * XS + r0]);
    float4 xb = *reinterpret_cast<const float4*>(&xT[k * XS + r0 + 4]);
    float4 wv = *reinterpret_cast<const float4*>(&ws[k * NC + c0]);
    float xr[8] = {xa.x, xa.y, xa.z, xa.w, xb.x, xb.y, xb.z, xb.w};
    float wr[4] = {wv.x, wv.y, wv.z, wv.w};
#pragma unroll
    for (int i = 0; i < 8; ++i)
#pragma unroll
      for (int j = 0; j < 4; ++j) acc2[i][j] = fmaf(xr[i], wr[j], acc2[i][j]);
  }
#pragma unroll
  for (int i = 0; i < 8; ++i) {
    int gr = brow + r0 + i;
    if (gr < N) {
      float4 o = make_float4(acc2[i][0], acc2[i][1], acc2[i][2], acc2[i][3]);
      *reinterpret_cast<float4*>(&out[(size_t)gr * NC + c0]) = o;
    }
  }
}

// ---------------------------------------------------------------------------
// Degree histograms: deg_i counts sources (for GCN norm), indeg counts
// destinations (for the pull-CSR). Int atomics -> deterministic.
__global__ __launch_bounds__(256) void hist_kernel(
    const int* __restrict__ ei, int* __restrict__ deg_i,
    int* __restrict__ indeg, int E) {
  int e = blockIdx.x * blockDim.x + threadIdx.x;
  if (e < E) {
    atomicAdd(&deg_i[ei[e]], 1);       // row = edge_index[0]
    atomicAdd(&indeg[ei[E + e]], 1);   // col = edge_index[1]
  }
}

// dis[i] = 1/sqrt(deg_i[i] + 1)   (+1 = self loop; deg always >= 1)
__global__ __launch_bounds__(256) void dis_kernel(
    const int* __restrict__ deg_i, float* __restrict__ dis, int N) {
  int i = blockIdx.x * blockDim.x + threadIdx.x;
  if (i < N) dis[i] = 1.0f / sqrtf((float)(deg_i[i] + 1));
}

// ---------------------------------------------------------------------------
// 3-kernel exclusive scan of indeg -> rowptr  (N = 50000, 196 blocks of 256)
__global__ __launch_bounds__(256) void scan_sum_kernel(
    const int* __restrict__ indeg, int* __restrict__ bsum, int N) {
  __shared__ int sm[256];
  int tid = threadIdx.x;
  int i = blockIdx.x * 256 + tid;
  sm[tid] = (i < N) ? indeg[i] : 0;
  __syncthreads();
  for (int s = 128; s > 0; s >>= 1) {
    if (tid < s) sm[tid] += sm[tid + s];
    __syncthreads();
  }
  if (tid == 0) bsum[blockIdx.x] = sm[0];
}

__global__ __launch_bounds__(256) void scan_bsum_kernel(int* __restrict__ bsum, int nb) {
  __shared__ int sm[256];
  int tid = threadIdx.x;
  int v = (tid < nb) ? bsum[tid] : 0;
  sm[tid] = v;
  __syncthreads();
  for (int s = 1; s < 256; s <<= 1) {
    int t = (tid >= s) ? sm[tid - s] : 0;
    __syncthreads();
    sm[tid] += t;
    __syncthreads();
  }
  if (tid < nb) bsum[tid] = sm[tid] - v;  // exclusive
}

__global__ __launch_bounds__(256) void scan_final_kernel(
    const int* __restrict__ indeg, const int* __restrict__ bsum,
    int* __restrict__ rowptr, int N) {
  __shared__ int sm[256];
  int tid = threadIdx.x;
  int i = blockIdx.x * 256 + tid;
  int v = (i < N) ? indeg[i] : 0;
  sm[tid] = v;
  __syncthreads();
  for (int s = 1; s < 256; s <<= 1) {
    int t = (tid >= s) ? sm[tid - s] : 0;
    __syncthreads();
    sm[tid] += t;
    __syncthreads();
  }
  if (i < N) rowptr[i] = bsum[blockIdx.x] + sm[tid] - v;
}

// ---------------------------------------------------------------------------
// Build destination-CSR entries: csr[pos] = {src, norm} packed as int2.
__global__ __launch_bounds__(256) void scatter_kernel(
    const int* __restrict__ ei, const int* __restrict__ rowptr,
    int* __restrict__ cursor, const float* __restrict__ dis,
    int2* __restrict__ csr, int E) {
  int e = blockIdx.x * blockDim.x + threadIdx.x;
  if (e < E) {
    int s = ei[e];
    int c = ei[E + e];
    int pos = rowptr[c] + atomicAdd(&cursor[c], 1);
    csr[pos] = make_int2(s, __float_as_int(dis[s] * dis[c]));
  }
}

// ---------------------------------------------------------------------------
// One adaptive-propagation step, fully fused. One 64-lane wave per node,
// lane = feature. Pull-based gather over incoming edges, no atomics.
__global__ __launch_bounds__(256) void prop_step_kernel(
    const float* __restrict__ prop, float* __restrict__ prop_new,
    const int2* __restrict__ csr, const int* __restrict__ rowptr,
    const float* __restrict__ dis, const float* __restrict__ hw,
    const float* __restrict__ hb, float* __restrict__ steps,
    float* __restrict__ sumh, int* __restrict__ cont,
    float* __restrict__ xacc, int N) {
  int wid = (int)((blockIdx.x * blockDim.x + threadIdx.x) >> 6);
  if (wid >= N) return;
  int lane = threadIdx.x & 63;
  size_t rowoff = (size_t)wid * NC + lane;

  float oldv = prop[rowoff];
  float dc = dis[wid];
  int beg = __builtin_amdgcn_readfirstlane(rowptr[wid]);
  int end = __builtin_amdgcn_readfirstlane(rowptr[wid + 1]);

  // self-loop: norm = dis[c]^2
  float a0 = dc * dc * oldv, a1 = 0.f, a2 = 0.f, a3 = 0.f;
  int i = beg;
  for (; i + 4 <= end; i += 4) {   // 4-way unroll: 4 outstanding gathers
    int2 e0 = csr[i], e1 = csr[i + 1], e2 = csr[i + 2], e3 = csr[i + 3];
    a0 = fmaf(__int_as_float(e0.y), prop[(size_t)e0.x * NC + lane], a0);
    a1 = fmaf(__int_as_float(e1.y), prop[(size_t)e1.x * NC + lane], a1);
    a2 = fmaf(__int_as_float(e2.y), prop[(size_t)e2.x * NC + lane], a2);
    a3 = fmaf(__int_as_float(e3.y), prop[(size_t)e3.x * NC + lane], a3);
  }
  for (; i < end; ++i) {
    int2 e0 = csr[i];
    a0 = fmaf(__int_as_float(e0.y), prop[(size_t)e0.x * NC + lane], a0);
  }
  float acc = (a0 + a1) + (a2 + a3);
  prop_new[rowoff] = acc;

  // hh = sigmoid(prop_new[c,:] . halt_w + halt_b)
  float z = acc * hw[lane];
#pragma unroll
  for (int off = 32; off > 0; off >>= 1) z += __shfl_xor(z, off);
  z += hb[0];
  float hh = 1.0f / (1.0f + expf(-z));

  float st = steps[wid], sh = sumh[wid];
  int ct = cont[wid];
  bool prob = ((sh + hh) < 0.99f) && (ct != 0);
  float pf = prob ? 1.0f : 0.0f;
  st += pf;
  sh += pf * hh;
  bool cond = prob && (st < (float)NITER);
  float pp = cond ? sh : (1.0f - sh);
  float ctf = ct ? 1.0f : 0.0f;
  xacc[rowoff] += (acc * pp + oldv * (1.0f - pp)) * ctf;
  if (lane == 0) { steps[wid] = st; sumh[wid] = sh; cont[wid] = prob ? 1 : 0; }
}

// ---------------------------------------------------------------------------
// out0 = log_softmax(xacc/steps), out1 = steps, out2 = 1 - sum_h
__global__ __launch_bounds__(256) void final_kernel(
    const float* __restrict__ xacc, const float* __restrict__ steps,
    const float* __restrict__ sumh, float* __restrict__ out0,
    float* __restrict__ out1, float* __restrict__ out2, int N) {
  int wid = (int)((blockIdx.x * blockDim.x + threadIdx.x) >> 6);
  if (wid >= N) return;
  int lane = threadIdx.x & 63;
  float st = steps[wid];
  float v = xacc[(size_t)wid * NC + lane] / st;
  float m = v;
#pragma unroll
  for (int off = 32; off > 0; off >>= 1) m = fmaxf(m, __shfl_xor(m, off));
  float e = expf(v - m);
  float s = e;
#pragma unroll
  for (int off = 32; off > 0; off >>= 1) s += __shfl_xor(s, off);
  out0[(size_t)wid * NC + lane] = v - m - logf(s);
  if (lane == 0) { out1[wid] = st; out2[wid] = 1.0f - sumh[wid]; }
}

// ---------------------------------------------------------------------------
extern "C" void kernel_launch(void* const* d_in, const int* in_sizes, int n_in,
                              void* d_out, int out_size, void* d_ws, size_t ws_size,
                              hipStream_t stream) {
  const float* x      = (const float*)d_in[0];
  const int*   ei     = (const int*)d_in[1];
  const float* W1     = (const float*)d_in[2];
  const float* b1     = (const float*)d_in[3];
  const float* W2     = (const float*)d_in[4];
  const float* b2     = (const float*)d_in[5];
  const float* halt_w = (const float*)d_in[6];
  const float* halt_b = (const float*)d_in[7];

  const int N = in_sizes[0] / F_IN;   // 50000
  const int E = in_sizes[1] / 2;      // 800000

  // workspace carve-up (256B aligned)
  char* p = (char*)d_ws;
  auto alloc = [&](size_t bytes) {
    void* r = (void*)p;
    p += (bytes + 255) & ~(size_t)255;
    return r;
  };
  float* propA  = (float*)alloc((size_t)N * NC * 4);
  float* propB  = (float*)alloc((size_t)N * NC * 4);
  float* xacc   = (float*)alloc((size_t)N * NC * 4);
  int2*  csr    = (int2*)alloc((size_t)E * 8);
  int*   rowptr = (int*)alloc((size_t)(N + 1) * 4);
  int*   deg_i  = (int*)alloc((size_t)N * 4);
  int*   indeg  = (int*)alloc((size_t)N * 4);
  int*   cursor = (int*)alloc((size_t)N * 4);
  float* dis    = (float*)alloc((size_t)N * 4);
  float* steps  = (float*)alloc((size_t)N * 4);
  float* sumh   = (float*)alloc((size_t)N * 4);
  int*   cont   = (int*)alloc((size_t)N * 4);
  int*   bsum   = (int*)alloc(1024);

  hipMemsetAsync(deg_i,  0, (size_t)N * 4, stream);
  hipMemsetAsync(indeg,  0, (size_t)N * 4, stream);
  hipMemsetAsync(cursor, 0, (size_t)N * 4, stream);
  hipMemsetAsync(xacc,   0, (size_t)N * NC * 4, stream);

  const int nbN = (N + 255) / 256;   // 196
  const int nbE = (E + 255) / 256;   // 3125
  const int nbM = (N + BM - 1) / BM; // 391

  init_state_kernel<<<nbN, 256, 0, stream>>>(steps, sumh, cont, rowptr, N, E);
  mlp_kernel<<<nbM, 256, 0, stream>>>(x, W1, b1, W2, b2, propA, N);
  hist_kernel<<<nbE, 256, 0, stream>>>(ei, deg_i, indeg, E);
  dis_kernel<<<nbN, 256, 0, stream>>>(deg_i, dis, N);
  scan_sum_kernel<<<nbN, 256, 0, stream>>>(indeg, bsum, N);
  scan_bsum_kernel<<<1, 256, 0, stream>>>(bsum, nbN);
  scan_final_kernel<<<nbN, 256, 0, stream>>>(indeg, bsum, rowptr, N);
  scatter_kernel<<<nbE, 256, 0, stream>>>(ei, rowptr, cursor, dis, csr, E);

  float* out0 = (float*)d_out;
  float* out1 = out0 + (size_t)N * NC;
  float* out2 = out1 + N;

  const float* cur = propA;
  float* nxt = propB;
  const int nbW = (N + 3) / 4;       // 4 waves (nodes) per 256-thread block
  for (int it = 0; it < NITER; ++it) {
    prop_step_kernel<<<nbW, 256, 0, stream>>>(cur, nxt, csr, rowptr, dis,
                                              halt_w, halt_b, steps, sumh,
                                              cont, xacc, N);
    const float* t = nxt; nxt = (float*)cur; cur = t;
  }
  final_kernel<<<nbW, 256, 0, stream>>>(xacc, steps, sumh, out0, out1, out2, N);
}

// Round 3
// 578.641 us; speedup vs baseline: 1.1749x; 1.0164x over previous
//
#include <hip/hip_runtime.h>
#include <hip/hip_bf16.h>

#define F_IN 512
#define NC 64      // HID == N_CLS == 64
#define NITER 10
#define BM 128     // MLP tile rows
#define BK 64      // MLP K tile
// xT layout: element (k, r) at xT[k*128 + (r ^ (k & 28))].
// Write banks: r ^ 4*(kq&7) -> 2-way (free). Reads stay b128-aligned.

// ---------------------------------------------------------------------------
// Init per-node halting state; also set rowptr[N] = E.
__global__ __launch_bounds__(256) void init_state_kernel(
    float* __restrict__ steps, float* __restrict__ sumh, int* __restrict__ cont,
    int* __restrict__ rowptr, int N, int E) {
  int i = blockIdx.x * blockDim.x + threadIdx.x;
  if (i < N) { steps[i] = 1.0f; sumh[i] = 0.0f; cont[i] = 1; }
  if (i == 0) rowptr[N] = E;
}

// ---------------------------------------------------------------------------
// Fused tiled MLP: out[r,:] = relu(x[r,:] @ W1 + b1) @ W2 + b2   (all fp32)
// Block: 128 rows x 64 cols, 256 threads, 8x4 outputs per thread.
// x tile staged transposed+swizzled in LDS; W tiles staged row-major.
// GEMM2 fused: h goes through LDS (same swizzled-transpose layout).
__global__ __launch_bounds__(256) void mlp_kernel(
    const float* __restrict__ x, const float* __restrict__ W1,
    const float* __restrict__ b1, const float* __restrict__ W2,
    const float* __restrict__ b2, float* __restrict__ out, int N) {
  __shared__ float xT[BK * 128];   // swizzled [k][row] x tile / later hT
  __shared__ float ws[BK * NC];    // W1 k-tile / later W2
  const int tid  = threadIdx.x;
  const int brow = blockIdx.x * BM;
  const int r0 = (tid >> 4) * 8;   // 16 row-groups of 8
  const int c0 = (tid & 15) * 4;   // 16 col-groups of 4

  float acc[8][4];
#pragma unroll
  for (int j = 0; j < 4; ++j) {
    float bv = b1[c0 + j];
#pragma unroll
    for (int i = 0; i < 8; ++i) acc[i][j] = bv;
  }

  for (int kt = 0; kt < F_IN; kt += BK) {
    // stage x tile (128 rows x 64 k), transposed+swizzled into xT
#pragma unroll
    for (int q = 0; q < 8; ++q) {
      int fidx = q * 256 + tid;          // over 2048 float4s
      int row = fidx >> 4, kq = fidx & 15;
      int gr = brow + row; if (gr >= N) gr = N - 1;
      float4 v = *reinterpret_cast<const float4*>(&x[(size_t)gr * F_IN + kt + kq * 4]);
      float vv[4] = {v.x, v.y, v.z, v.w};
#pragma unroll
      for (int j = 0; j < 4; ++j) {
        int kk = kq * 4 + j;
        xT[kk * 128 + (row ^ (kk & 28))] = vv[j];
      }
    }
    // stage W1 k-tile (64 x 64), row-major
#pragma unroll
    for (int q = 0; q < 4; ++q) {
      int fidx = q * 256 + tid;          // over 1024 float4s
      int row = fidx >> 4, kq = fidx & 15;
      *reinterpret_cast<float4*>(&ws[row * NC + kq * 4]) =
          *reinterpret_cast<const float4*>(&W1[(size_t)(kt + row) * NC + kq * 4]);
    }
    __syncthreads();
#pragma unroll 4
    for (int k = 0; k < BK; ++k) {
      float4 xa = *reinterpret_cast<const float4*>(&xT[k * 128 + (r0 ^ (k & 28))]);
      float4 xb = *reinterpret_cast<const float4*>(&xT[k * 128 + ((r0 + 4) ^ (k & 28))]);
      float4 wv = *reinterpret_cast<const float4*>(&ws[k * NC + c0]);
      float xr[8] = {xa.x, xa.y, xa.z, xa.w, xb.x, xb.y, xb.z, xb.w};
      float wr[4] = {wv.x, wv.y, wv.z, wv.w};
#pragma unroll
      for (int i = 0; i < 8; ++i)
#pragma unroll
        for (int j = 0; j < 4; ++j) acc[i][j] = fmaf(xr[i], wr[j], acc[i][j]);
    }
    __syncthreads();
  }

  // ReLU; write h transposed+swizzled into xT space; stage W2 into ws
#pragma unroll
  for (int i = 0; i < 8; ++i)
#pragma unroll
    for (int j = 0; j < 4; ++j) {
      int kk = c0 + j;
      int r  = r0 + i;
      xT[kk * 128 + (r ^ (kk & 28))] = fmaxf(acc[i][j], 0.0f);
    }
#pragma unroll
  for (int q = 0; q < 4; ++q) {
    int fidx = q * 256 + tid;
    int row = fidx >> 4, kq = fidx & 15;
    *reinterpret_cast<float4*>(&ws[row * NC + kq * 4]) =
        *reinterpret_cast<const float4*>(&W2[(size_t)row * NC + kq * 4]);
  }
  float acc2[8][4];
#pragma unroll
  for (int j = 0; j < 4; ++j) {
    float bv = b2[c0 + j];
#pragma unroll
    for (int i = 0; i < 8; ++i) acc2[i][j] = bv;
  }
  __syncthreads();
#pragma unroll 4
  for (int k = 0; k < NC; ++k) {
    float4 xa = *reinterpret_cast<const float4*>(&xT[k * 128 + (r0 ^ (k & 28))]);
    float4 xb = *reinterpret_cast<const float4*>(&xT[k * 128 + ((r0 + 4) ^ (k & 28))]);
    float4 wv = *reinterpret_cast<const float4*>(&ws[k * NC + c0]);
    float xr[8] = {xa.x, xa.y, xa.z, xa.w, xb.x, xb.y, xb.z, xb.w};
    float wr[4] = {wv.x, wv.y, wv.z, wv.w};
#pragma unroll
    for (int i = 0; i < 8; ++i)
#pragma unroll
      for (int j = 0; j < 4; ++j) acc2[i][j] = fmaf(xr[i], wr[j], acc2[i][j]);
  }
#pragma unroll
  for (int i = 0; i < 8; ++i) {
    int gr = brow + r0 + i;
    if (gr < N) {
      float4 o = make_float4(acc2[i][0], acc2[i][1], acc2[i][2], acc2[i][3]);
      *reinterpret_cast<float4*>(&out[(size_t)gr * NC + c0]) = o;
    }
  }
}

// ---------------------------------------------------------------------------
// Degree histograms: deg_i counts sources (for GCN norm), indeg counts
// destinations (for the pull-CSR). Int atomics -> deterministic.
__global__ __launch_bounds__(256) void hist_kernel(
    const int* __restrict__ ei, int* __restrict__ deg_i,
    int* __restrict__ indeg, int E) {
  int e = blockIdx.x * blockDim.x + threadIdx.x;
  if (e < E) {
    atomicAdd(&deg_i[ei[e]], 1);       // row = edge_index[0]
    atomicAdd(&indeg[ei[E + e]], 1);   // col = edge_index[1]
  }
}

// dis[i] = 1/sqrt(deg_i[i] + 1)   (+1 = self loop; deg always >= 1)
__global__ __launch_bounds__(256) void dis_kernel(
    const int* __restrict__ deg_i, float* __restrict__ dis, int N) {
  int i = blockIdx.x * blockDim.x + threadIdx.x;
  if (i < N) dis[i] = 1.0f / sqrtf((float)(deg_i[i] + 1));
}

// ---------------------------------------------------------------------------
// 3-kernel exclusive scan of indeg -> rowptr  (N = 50000, 196 blocks of 256)
__global__ __launch_bounds__(256) void scan_sum_kernel(
    const int* __restrict__ indeg, int* __restrict__ bsum, int N) {
  __shared__ int sm[256];
  int tid = threadIdx.x;
  int i = blockIdx.x * 256 + tid;
  sm[tid] = (i < N) ? indeg[i] : 0;
  __syncthreads();
  for (int s = 128; s > 0; s >>= 1) {
    if (tid < s) sm[tid] += sm[tid + s];
    __syncthreads();
  }
  if (tid == 0) bsum[blockIdx.x] = sm[0];
}

__global__ __launch_bounds__(256) void scan_bsum_kernel(int* __restrict__ bsum, int nb) {
  __shared__ int sm[256];
  int tid = threadIdx.x;
  int v = (tid < nb) ? bsum[tid] : 0;
  sm[tid] = v;
  __syncthreads();
  for (int s = 1; s < 256; s <<= 1) {
    int t = (tid >= s) ? sm[tid - s] : 0;
    __syncthreads();
    sm[tid] += t;
    __syncthreads();
  }
  if (tid < nb) bsum[tid] = sm[tid] - v;  // exclusive
}

__global__ __launch_bounds__(256) void scan_final_kernel(
    const int* __restrict__ indeg, const int* __restrict__ bsum,
    int* __restrict__ rowptr, int N) {
  __shared__ int sm[256];
  int tid = threadIdx.x;
  int i = blockIdx.x * 256 + tid;
  int v = (i < N) ? indeg[i] : 0;
  sm[tid] = v;
  __syncthreads();
  for (int s = 1; s < 256; s <<= 1) {
    int t = (tid >= s) ? sm[tid - s] : 0;
    __syncthreads();
    sm[tid] += t;
    __syncthreads();
  }
  if (i < N) rowptr[i] = bsum[blockIdx.x] + sm[tid] - v;
}

// ---------------------------------------------------------------------------
// Build destination-CSR entries: csr[pos] = {src, norm} packed as int2.
__global__ __launch_bounds__(256) void scatter_kernel(
    const int* __restrict__ ei, const int* __restrict__ rowptr,
    int* __restrict__ cursor, const float* __restrict__ dis,
    int2* __restrict__ csr, int E) {
  int e = blockIdx.x * blockDim.x + threadIdx.x;
  if (e < E) {
    int s = ei[e];
    int c = ei[E + e];
    int pos = rowptr[c] + atomicAdd(&cursor[c], 1);
    csr[pos] = make_int2(s, __float_as_int(dis[s] * dis[c]));
  }
}

// ---------------------------------------------------------------------------
// One adaptive-propagation step, fully fused. One 64-lane wave per node,
// lane = feature. Pull-based gather over incoming edges, no atomics.
// 8 accumulators -> 8 outstanding gathers to cover L2/L3 latency.
__global__ __launch_bounds__(256) void prop_step_kernel(
    const float* __restrict__ prop, float* __restrict__ prop_new,
    const int2* __restrict__ csr, const int* __restrict__ rowptr,
    const float* __restrict__ dis, const float* __restrict__ hw,
    const float* __restrict__ hb, float* __restrict__ steps,
    float* __restrict__ sumh, int* __restrict__ cont,
    float* __restrict__ xacc, int N) {
  int wid = (int)((blockIdx.x * blockDim.x + threadIdx.x) >> 6);
  if (wid >= N) return;
  int lane = threadIdx.x & 63;
  size_t rowoff = (size_t)wid * NC + lane;

  float oldv = prop[rowoff];
  float dc = dis[wid];
  int beg = __builtin_amdgcn_readfirstlane(rowptr[wid]);
  int end = __builtin_amdgcn_readfirstlane(rowptr[wid + 1]);

  // self-loop: norm = dis[c]^2
  float a[8];
  a[0] = dc * dc * oldv;
#pragma unroll
  for (int u = 1; u < 8; ++u) a[u] = 0.0f;
  int i = beg;
  for (; i + 8 <= end; i += 8) {   // 8 outstanding gathers
    int2 e[8];
#pragma unroll
    for (int u = 0; u < 8; ++u) e[u] = csr[i + u];
#pragma unroll
    for (int u = 0; u < 8; ++u)
      a[u] = fmaf(__int_as_float(e[u].y), prop[(size_t)e[u].x * NC + lane], a[u]);
  }
  for (; i < end; ++i) {
    int2 e0 = csr[i];
    a[0] = fmaf(__int_as_float(e0.y), prop[(size_t)e0.x * NC + lane], a[0]);
  }
  float acc = ((a[0] + a[1]) + (a[2] + a[3])) + ((a[4] + a[5]) + (a[6] + a[7]));
  prop_new[rowoff] = acc;

  // hh = sigmoid(prop_new[c,:] . halt_w + halt_b)
  float z = acc * hw[lane];
#pragma unroll
  for (int off = 32; off > 0; off >>= 1) z += __shfl_xor(z, off);
  z += hb[0];
  float hh = 1.0f / (1.0f + expf(-z));

  float st = steps[wid], sh = sumh[wid];
  int ct = cont[wid];
  bool prob = ((sh + hh) < 0.99f) && (ct != 0);
  float pf = prob ? 1.0f : 0.0f;
  st += pf;
  sh += pf * hh;
  bool cond = prob && (st < (float)NITER);
  float pp = cond ? sh : (1.0f - sh);
  float ctf = ct ? 1.0f : 0.0f;
  xacc[rowoff] += (acc * pp + oldv * (1.0f - pp)) * ctf;
  if (lane == 0) { steps[wid] = st; sumh[wid] = sh; cont[wid] = prob ? 1 : 0; }
}

// ---------------------------------------------------------------------------
// out0 = log_softmax(xacc/steps), out1 = steps, out2 = 1 - sum_h
__global__ __launch_bounds__(256) void final_kernel(
    const float* __restrict__ xacc, const float* __restrict__ steps,
    const float* __restrict__ sumh, float* __restrict__ out0,
    float* __restrict__ out1, float* __restrict__ out2, int N) {
  int wid = (int)((blockIdx.x * blockDim.x + threadIdx.x) >> 6);
  if (wid >= N) return;
  int lane = threadIdx.x & 63;
  float st = steps[wid];
  float v = xacc[(size_t)wid * NC + lane] / st;
  float m = v;
#pragma unroll
  for (int off = 32; off > 0; off >>= 1) m = fmaxf(m, __shfl_xor(m, off));
  float e = expf(v - m);
  float s = e;
#pragma unroll
  for (int off = 32; off > 0; off >>= 1) s += __shfl_xor(s, off);
  out0[(size_t)wid * NC + lane] = v - m - logf(s);
  if (lane == 0) { out1[wid] = st; out2[wid] = 1.0f - sumh[wid]; }
}

// ---------------------------------------------------------------------------
extern "C" void kernel_launch(void* const* d_in, const int* in_sizes, int n_in,
                              void* d_out, int out_size, void* d_ws, size_t ws_size,
                              hipStream_t stream) {
  const float* x      = (const float*)d_in[0];
  const int*   ei     = (const int*)d_in[1];
  const float* W1     = (const float*)d_in[2];
  const float* b1     = (const float*)d_in[3];
  const float* W2     = (const float*)d_in[4];
  const float* b2     = (const float*)d_in[5];
  const float* halt_w = (const float*)d_in[6];
  const float* halt_b = (const float*)d_in[7];

  const int N = in_sizes[0] / F_IN;   // 50000
  const int E = in_sizes[1] / 2;      // 800000

  // workspace carve-up (256B aligned)
  char* p = (char*)d_ws;
  auto alloc = [&](size_t bytes) {
    void* r = (void*)p;
    p += (bytes + 255) & ~(size_t)255;
    return r;
  };
  float* propA  = (float*)alloc((size_t)N * NC * 4);
  float* propB  = (float*)alloc((size_t)N * NC * 4);
  float* xacc   = (float*)alloc((size_t)N * NC * 4);
  int2*  csr    = (int2*)alloc((size_t)E * 8);
  int*   rowptr = (int*)alloc((size_t)(N + 1) * 4);
  int*   deg_i  = (int*)alloc((size_t)N * 4);
  int*   indeg  = (int*)alloc((size_t)N * 4);
  int*   cursor = (int*)alloc((size_t)N * 4);
  float* dis    = (float*)alloc((size_t)N * 4);
  float* steps  = (float*)alloc((size_t)N * 4);
  float* sumh   = (float*)alloc((size_t)N * 4);
  int*   cont   = (int*)alloc((size_t)N * 4);
  int*   bsum   = (int*)alloc(1024);

  hipMemsetAsync(deg_i,  0, (size_t)N * 4, stream);
  hipMemsetAsync(indeg,  0, (size_t)N * 4, stream);
  hipMemsetAsync(cursor, 0, (size_t)N * 4, stream);
  hipMemsetAsync(xacc,   0, (size_t)N * NC * 4, stream);

  const int nbN = (N + 255) / 256;   // 196
  const int nbE = (E + 255) / 256;   // 3125
  const int nbM = (N + BM - 1) / BM; // 391

  init_state_kernel<<<nbN, 256, 0, stream>>>(steps, sumh, cont, rowptr, N, E);
  mlp_kernel<<<nbM, 256, 0, stream>>>(x, W1, b1, W2, b2, propA, N);
  hist_kernel<<<nbE, 256, 0, stream>>>(ei, deg_i, indeg, E);
  dis_kernel<<<nbN, 256, 0, stream>>>(deg_i, dis, N);
  scan_sum_kernel<<<nbN, 256, 0, stream>>>(indeg, bsum, N);
  scan_bsum_kernel<<<1, 256, 0, stream>>>(bsum, nbN);
  scan_final_kernel<<<nbN, 256, 0, stream>>>(indeg, bsum, rowptr, N);
  scatter_kernel<<<nbE, 256, 0, stream>>>(ei, rowptr, cursor, dis, csr, E);

  float* out0 = (float*)d_out;
  float* out1 = out0 + (size_t)N * NC;
  float* out2 = out1 + N;

  const float* cur = propA;
  float* nxt = propB;
  const int nbW = (N + 3) / 4;       // 4 waves (nodes) per 256-thread block
  for (int it = 0; it < NITER; ++it) {
    prop_step_kernel<<<nbW, 256, 0, stream>>>(cur, nxt, csr, rowptr, dis,
                                              halt_w, halt_b, steps, sumh,
                                              cont, xacc, N);
    const float* t = nxt; nxt = (float*)cur; cur = t;
  }
  final_kernel<<<nbW, 256, 0, stream>>>(xacc, steps, sumh, out0, out1, out2, N);
}